// Round 3
// baseline (263.930 us; speedup 1.0000x reference)
//
#include <hip/hip_runtime.h>

// StyleLossDiag: x [16,512,64,64] f32, target [8192] f32 -> scalar f32.
// g[row] = sum(x[row,:]^2) / 2^25 ; loss = mean((g - target)^2).
// Memory-bound: 134 MB read -> ~21.3 us floor at 6.3 TB/s achievable.
//
// Single fused kernel + 4-byte memset node. The memset zeroes the ticket
// counter every launch, so the block drawing ticket ROWS-1 is genuinely the
// LAST arrival (round-2 bug: poisoned counter start made the winner early,
// reading ~2730 rows stale). Release fence before atomicAdd + acquire fence
// after guarantees all other rows' ws writes are visible to the finisher.
// Finisher sums in fixed index order -> bitwise-deterministic output.

#define ROWS   8192
#define ROWLEN 4096
// 16*512*64*64 = 2^25 -> exact power-of-two reciprocal
#define INV_NORM (1.0f / 33554432.0f)

__global__ __launch_bounds__(256) void styleloss_fused_kernel(
    const float* __restrict__ x,
    const float* __restrict__ target,
    float* __restrict__ ws,          // [ROWS] partials, counter at ws[ROWS]
    float* __restrict__ out)
{
    const int row = blockIdx.x;
    const float4* xr = reinterpret_cast<const float4*>(x) + (size_t)row * (ROWLEN / 4);

    // 256 threads * 4 float4 = 4096 elements, fully coalesced
    float s = 0.0f;
#pragma unroll
    for (int i = 0; i < 4; ++i) {
        float4 v = xr[threadIdx.x + i * 256];
        s += v.x * v.x + v.y * v.y + v.z * v.z + v.w * v.w;
    }

    // 64-lane wave reduce
#pragma unroll
    for (int off = 32; off > 0; off >>= 1)
        s += __shfl_down(s, off, 64);

    __shared__ float lds[4];
    __shared__ bool last;
    const int lane = threadIdx.x & 63;
    const int wave = threadIdx.x >> 6;
    if (lane == 0) lds[wave] = s;
    __syncthreads();

    if (threadIdx.x == 0) {
        float tot = (lds[0] + lds[1]) + (lds[2] + lds[3]);
        float d = tot * INV_NORM - target[row];
        ws[row] = d * d;
        __threadfence();  // release: ws[row] visible before the ticket
        unsigned* counter = reinterpret_cast<unsigned*>(ws) + ROWS;
        unsigned old = atomicAdd(counter, 1u);
        // counter is memset to 0 before this kernel -> ticket ROWS-1 is the
        // genuinely-last arrival of THIS launch
        last = (old == ROWS - 1);
    }
    __syncthreads();

    if (last) {
        __threadfence();  // acquire: pairs with writers' release via RMW chain
        const volatile float* wsv = ws;  // no register/L1 caching of partials
        float t = 0.0f;
#pragma unroll
        for (int i = 0; i < ROWS / 256; ++i)
            t += wsv[threadIdx.x + i * 256];

#pragma unroll
        for (int off = 32; off > 0; off >>= 1)
            t += __shfl_down(t, off, 64);

        if (lane == 0) lds[wave] = t;
        __syncthreads();

        if (threadIdx.x == 0)
            out[0] = ((lds[0] + lds[1]) + (lds[2] + lds[3])) * (1.0f / (float)ROWS);
    }
}

extern "C" void kernel_launch(void* const* d_in, const int* in_sizes, int n_in,
                              void* d_out, int out_size, void* d_ws, size_t ws_size,
                              hipStream_t stream)
{
    const float* x      = (const float*)d_in[0];   // [16,512,64,64]
    const float* target = (const float*)d_in[1];   // [8192]
    float* out = (float*)d_out;                    // [1]
    float* ws  = (float*)d_ws;                     // >= (8192+1) floats

    // zero the ticket counter every launch (graph-capturable memset node)
    hipMemsetAsync((char*)d_ws + ROWS * sizeof(float), 0, sizeof(unsigned), stream);
    styleloss_fused_kernel<<<ROWS, 256, 0, stream>>>(x, target, ws, out);
}

// Round 4
// 119.517 us; speedup vs baseline: 2.2083x; 2.2083x over previous
//
#include <hip/hip_runtime.h>

// StyleLossDiag: x [16,512,64,64] f32, target [8192] f32 -> scalar f32.
// g[row] = sum(x[row,:]^2) / 2^25 ; loss = mean((g - target)^2).
// Memory-bound: 134 MB read, ~21.3 us HBM floor (less when L3-warm).
//
// Round-1 structure (one block per row, 4x float4/thread, tree reduce =
// measured ~5.8 TB/s) but the second reduce kernel is replaced by one
// device-scope atomicAdd per block into out[0], zeroed each launch by a
// 4-byte memset node. No __threadfence (round-3 lesson: 8192 per-block
// device fences serialize at L2 -> 10x regression). Atomic ordering noise
// ~1e-15, two orders below the 2.96e-13 validation threshold.

#define ROWS   8192
#define ROWLEN 4096
// 16*512*64*64 = 2^25 -> exact power-of-two reciprocal
#define INV_NORM (1.0f / 33554432.0f)

__global__ __launch_bounds__(256) void styleloss_atomic_kernel(
    const float* __restrict__ x,
    const float* __restrict__ target,
    float* __restrict__ out)
{
    const int row = blockIdx.x;
    const float4* xr = reinterpret_cast<const float4*>(x) + (size_t)row * (ROWLEN / 4);

    // 256 threads * 4 float4 = 4096 elements, fully coalesced
    float s = 0.0f;
#pragma unroll
    for (int i = 0; i < 4; ++i) {
        float4 v = xr[threadIdx.x + i * 256];
        s += v.x * v.x + v.y * v.y + v.z * v.z + v.w * v.w;
    }

    // 64-lane wave butterfly reduce
#pragma unroll
    for (int off = 32; off > 0; off >>= 1)
        s += __shfl_down(s, off, 64);

    __shared__ float lds[4];
    const int lane = threadIdx.x & 63;
    const int wave = threadIdx.x >> 6;
    if (lane == 0) lds[wave] = s;
    __syncthreads();

    if (threadIdx.x == 0) {
        float tot = (lds[0] + lds[1]) + (lds[2] + lds[3]);
        float d = tot * INV_NORM - target[row];
        // contribute this row's share of the mean; out[0] zeroed per launch
        atomicAdd(out, d * d * (1.0f / (float)ROWS));
    }
}

extern "C" void kernel_launch(void* const* d_in, const int* in_sizes, int n_in,
                              void* d_out, int out_size, void* d_ws, size_t ws_size,
                              hipStream_t stream)
{
    const float* x      = (const float*)d_in[0];   // [16,512,64,64]
    const float* target = (const float*)d_in[1];   // [8192]
    float* out = (float*)d_out;                    // [1]

    // zero the accumulator every launch (graph-capturable memset node)
    hipMemsetAsync(d_out, 0, sizeof(float), stream);
    styleloss_atomic_kernel<<<ROWS, 256, 0, stream>>>(x, target, out);
}

// Round 5
// 26.903 us; speedup vs baseline: 9.8106x; 4.4426x over previous
//
#include <hip/hip_runtime.h>

// StyleLossDiag: x [16,512,64,64] f32, target [8192] f32 -> scalar f32.
// g[row] = sum(x[row,:]^2) / 2^25 ; loss = mean((g - target)^2).
// Memory-bound: 134 MB read; m13 ceiling 6.29 TB/s -> ~21.3 us floor, plus
// one tiny dependent dispatch (~2 us). Two-kernel structure is forced:
// round-3/4 lesson = per-block same-address device atomics/fences cost
// ~11-37 ns EACH serialized (8192 of them = 90-300 us). Dispatch-boundary
// coherence between dependent kernels is free.
//
// kernel1: one WAVE per row (4 waves/block, no LDS, no __syncthreads) --
// 16 independent float4 loads/lane into 4 accumulators for deep MLP, then
// a 6-step shfl tree; lane 0 writes (g-t)^2. Fixed order -> deterministic.
// kernel2: 1 block, float4 loads, fixed-order tree -> out[0].

#define ROWS     8192
#define ROWLEN   4096
// 16*512*64*64 = 2^25 -> exact power-of-two reciprocal
#define INV_NORM (1.0f / 33554432.0f)

__global__ __launch_bounds__(256) void rowdiag_wave_kernel(
    const float* __restrict__ x,
    const float* __restrict__ target,
    float* __restrict__ ws)
{
    const int wave = threadIdx.x >> 6;
    const int lane = threadIdx.x & 63;
    const int row  = blockIdx.x * 4 + wave;

    // this wave owns the whole row: 4096 elems / 64 lanes = 16 float4/lane
    const float4* xr = reinterpret_cast<const float4*>(x) + (size_t)row * (ROWLEN / 4);

    float a0 = 0.f, a1 = 0.f, a2 = 0.f, a3 = 0.f;
#pragma unroll
    for (int i = 0; i < 4; ++i) {
        // 4 independent loads per iteration, 4 accumulators: no dep chain
        float4 v0 = xr[lane + (4 * i + 0) * 64];
        float4 v1 = xr[lane + (4 * i + 1) * 64];
        float4 v2 = xr[lane + (4 * i + 2) * 64];
        float4 v3 = xr[lane + (4 * i + 3) * 64];
        a0 += v0.x * v0.x + v0.y * v0.y + v0.z * v0.z + v0.w * v0.w;
        a1 += v1.x * v1.x + v1.y * v1.y + v1.z * v1.z + v1.w * v1.w;
        a2 += v2.x * v2.x + v2.y * v2.y + v2.z * v2.z + v2.w * v2.w;
        a3 += v3.x * v3.x + v3.y * v3.y + v3.z * v3.z + v3.w * v3.w;
    }
    float s = (a0 + a1) + (a2 + a3);

    // 64-lane tree reduce, fixed order
#pragma unroll
    for (int off = 32; off > 0; off >>= 1)
        s += __shfl_down(s, off, 64);

    if (lane == 0) {
        float d = s * INV_NORM - target[row];
        ws[row] = d * d;
    }
}

__global__ __launch_bounds__(256) void final_reduce_kernel(
    const float* __restrict__ ws,
    float* __restrict__ out)
{
    const float4* w4 = reinterpret_cast<const float4*>(ws);
    float s = 0.f;
#pragma unroll
    for (int i = 0; i < ROWS / 4 / 256; ++i) {   // 8 float4 per thread
        float4 v = w4[threadIdx.x + i * 256];
        s += (v.x + v.y) + (v.z + v.w);
    }

#pragma unroll
    for (int off = 32; off > 0; off >>= 1)
        s += __shfl_down(s, off, 64);

    __shared__ float lds[4];
    const int lane = threadIdx.x & 63;
    const int wave = threadIdx.x >> 6;
    if (lane == 0) lds[wave] = s;
    __syncthreads();

    if (threadIdx.x == 0)
        out[0] = ((lds[0] + lds[1]) + (lds[2] + lds[3])) * (1.0f / (float)ROWS);
}

extern "C" void kernel_launch(void* const* d_in, const int* in_sizes, int n_in,
                              void* d_out, int out_size, void* d_ws, size_t ws_size,
                              hipStream_t stream)
{
    const float* x      = (const float*)d_in[0];   // [16,512,64,64]
    const float* target = (const float*)d_in[1];   // [8192]
    float* out = (float*)d_out;                    // [1]
    float* ws  = (float*)d_ws;                     // >= 8192 floats

    rowdiag_wave_kernel<<<ROWS / 4, 256, 0, stream>>>(x, target, ws);
    final_reduce_kernel<<<1, 256, 0, stream>>>(ws, out);
}